// Round 6
// baseline (25.179 us; speedup 1.0000x reference)
//
#include <hip/hip_runtime.h>

// Problem constants (match reference)
#define T_LEN   4096
#define NKNOT   6          // KNOT+2
#define NSEG    5          // KNOT+1
#define STEP    819        // (T_LEN-1)/(KNOT+1) == 4095/5, exact integer
#define B_SZ    128
#define C_CH    32
#define P_THR   0.5f

typedef float f32x4 __attribute__((ext_vector_type(4)));

// ---------------------------------------------------------------------------
// Compile-time: solve 6x6 not-a-knot system, then express each segment's
// basis weight as a plain cubic in t:  w_k(t) = e0 + e1*t + e2*t^2 + e3*t^3.
// Runtime folds with y into one float4 {E0,E1,E2,E3} per segment.
// ---------------------------------------------------------------------------
struct PolyCoefs { float e[NSEG][NKNOT][4]; };

constexpr double cabs_(double x) { return x < 0.0 ? -x : x; }

constexpr PolyCoefs compute_poly() {
    double A[NKNOT][NKNOT] = {}, R[NKNOT][NKNOT] = {};
    const double h = (double)STEP;
    for (int i = 1; i <= NKNOT - 2; ++i) {
        A[i][i-1] = h;       A[i][i] = 4.0 * h;   A[i][i+1] = h;
        R[i][i-1] = 6.0/h;   R[i][i] = -12.0/h;   R[i][i+1] = 6.0/h;
    }
    A[0][0] = h;              A[0][1] = -2.0*h;             A[0][2] = h;
    A[NKNOT-1][NKNOT-3] = h;  A[NKNOT-1][NKNOT-2] = -2.0*h; A[NKNOT-1][NKNOT-1] = h;
    for (int col = 0; col < NKNOT; ++col) {
        int piv = col;
        for (int r = col + 1; r < NKNOT; ++r)
            if (cabs_(A[r][col]) > cabs_(A[piv][col])) piv = r;
        if (piv != col) {
            for (int k = 0; k < NKNOT; ++k) {
                double t = A[col][k]; A[col][k] = A[piv][k]; A[piv][k] = t;
                t = R[col][k]; R[col][k] = R[piv][k]; R[piv][k] = t;
            }
        }
        double dinv = 1.0 / A[col][col];
        for (int k = 0; k < NKNOT; ++k) { A[col][k] *= dinv; R[col][k] *= dinv; }
        for (int r = 0; r < NKNOT; ++r) {
            if (r == col) continue;
            double f = A[r][col];
            for (int k = 0; k < NKNOT; ++k) {
                A[r][k] -= f * A[col][k];
                R[r][k] -= f * R[col][k];
            }
        }
    }
    PolyCoefs out{};
    for (int s = 0; s < NSEG; ++s) {
        const double ts = s * h, tr = (s + 1) * h;
        for (int k = 0; k < NKNOT; ++k) {
            double Si = R[s][k], Sj = R[s+1][k];
            double Yi = (s == k)     ? 1.0 : 0.0;
            double Yj = (s + 1 == k) ? 1.0 : 0.0;
            double a = Si / (6.0 * h), b = Sj / (6.0 * h);
            double c = (Yi - Si * h * h / 6.0) / h;
            double d = (Yj - Sj * h * h / 6.0) / h;
            out.e[s][k][0] = (float)( a*tr*tr*tr - b*ts*ts*ts + c*tr - d*ts);
            out.e[s][k][1] = (float)(-3.0*a*tr*tr + 3.0*b*ts*ts - c + d);
            out.e[s][k][2] = (float)( 3.0*a*tr - 3.0*b*ts);
            out.e[s][k][3] = (float)( b - a);
        }
    }
    return out;
}

__device__ constexpr PolyCoefs POLY = compute_poly();

// ---------------------------------------------------------------------------
// One block per TWO (b,c) rows: halves per-byte prologue/sync/launch cost.
// All 8 f32x4 loads issued before the coefficient prologue (128 B/thread MLP).
// Horner-in-t eval, one LDS broadcast per float4 chunk.
// ---------------------------------------------------------------------------
__global__ __launch_bounds__(256) void magwarp(
    const float* __restrict__ x, const float* __restrict__ yy,
    const float* __restrict__ mask_u, float* __restrict__ out) {
    const int tid = threadIdx.x;
    const int bc0 = blockIdx.x * 2;
    const int bc1 = bc0 + 1;
    const int b0 = bc0 >> 5, c0 = bc0 & (C_CH - 1);
    const int b1 = bc1 >> 5, c1 = bc1 & (C_CH - 1);
    const bool ap0 = mask_u[b0] < P_THR;
    const bool ap1 = mask_u[b1] < P_THR;

    const f32x4* xp0 = (const f32x4*)(x + (size_t)bc0 * T_LEN);
    const f32x4* xp1 = (const f32x4*)(x + (size_t)bc1 * T_LEN);
    f32x4*       op0 = (f32x4*)(out + (size_t)bc0 * T_LEN);
    f32x4*       op1 = (f32x4*)(out + (size_t)bc1 * T_LEN);

    // Issue all 8 loads before the prologue.
    f32x4 r0a = xp0[tid], r0b = xp0[tid + 256], r0c = xp0[tid + 512], r0d = xp0[tid + 768];
    f32x4 r1a = xp1[tid], r1b = xp1[tid + 256], r1c = xp1[tid + 512], r1d = xp1[tid + 768];

    __shared__ f32x4 cs[2][NSEG];         // {E0,E1,E2,E3} per row, per segment
    if (tid < 2 * NSEG) {
        const int r = tid / NSEG, s = tid % NSEG;
        const bool ap = r ? ap1 : ap0;
        if (ap) {
            const int bb = r ? b1 : b0, cc = r ? c1 : c0;
            float e0 = 0.f, e1 = 0.f, e2 = 0.f, e3 = 0.f;
            #pragma unroll
            for (int k = 0; k < NKNOT; ++k) {
                float y = yy[(bb * NKNOT + k) * C_CH + cc];
                e0 += POLY.e[s][k][0] * y;
                e1 += POLY.e[s][k][1] * y;
                e2 += POLY.e[s][k][2] * y;
                e3 += POLY.e[s][k][3] * y;
            }
            cs[r][s] = (f32x4){e0, e1, e2, e3};
        }
    }
    __syncthreads();

    const float inv_step = 1.0f / (float)STEP;
    #define PROC(row, v, i0)                                               \
    {                                                                      \
        const float t0f = (float)((i0) * 4);                               \
        int seg = (int)(t0f * inv_step);                                   \
        seg = seg > NSEG - 1 ? NSEG - 1 : seg;                             \
        const f32x4 cf = cs[row][seg];    /* ds_read_b128, broadcast */    \
        _Pragma("unroll")                                                  \
        for (int j = 0; j < 4; ++j) {                                      \
            const float tf = t0f + (float)j;                               \
            const float r = ((cf.w * tf + cf.z) * tf + cf.y) * tf + cf.x;  \
            (v)[j] *= r;                                                   \
        }                                                                  \
    }

    if (ap0) {
        PROC(0, r0a, tid);       PROC(0, r0b, tid + 256);
        PROC(0, r0c, tid + 512); PROC(0, r0d, tid + 768);
    }
    op0[tid]       = r0a;
    op0[tid + 256] = r0b;
    op0[tid + 512] = r0c;
    op0[tid + 768] = r0d;

    if (ap1) {
        PROC(1, r1a, tid);       PROC(1, r1b, tid + 256);
        PROC(1, r1c, tid + 512); PROC(1, r1d, tid + 768);
    }
    op1[tid]       = r1a;
    op1[tid + 256] = r1b;
    op1[tid + 512] = r1c;
    op1[tid + 768] = r1d;
    #undef PROC
}

// ---------------------------------------------------------------------------
extern "C" void kernel_launch(void* const* d_in, const int* in_sizes, int n_in,
                              void* d_out, int out_size, void* d_ws, size_t ws_size,
                              hipStream_t stream) {
    const float* x   = (const float*)d_in[0];   // (128, 32, 4096) f32
    const float* yy  = (const float*)d_in[1];   // (128, 6, 32)    f32
    const float* mu  = (const float*)d_in[2];   // (128, 1, 1)     f32
    float*       out = (float*)d_out;

    const int nblocks = (B_SZ * C_CH) / 2;      // 2048
    hipLaunchKernelGGL(magwarp, dim3(nblocks), dim3(256), 0, stream,
                       x, yy, mu, out);
}